// Round 1
// baseline (232.685 us; speedup 1.0000x reference)
//
#include <hip/hip_runtime.h>

#define N_WORDS 16384
#define EMB 128
#define NROOTS 2048
#define EPS 1e-8f
#define LOG2_BOOST 0.5849625007211562f   // log2(1.5)

// ws layout (bytes):
//   [0,      8192)   counts   int[2048]
//   [8192,   8196)   denom    float
//   [16384,  81920)  roots    int[16384]
//   [81920, 147456)  x        float[16384]   (w*boost^c + eps)
//   [147456,1196032) g        float[2048*128] (per-root transformed emb)

__global__ void k_roots_hist(const int* __restrict__ wi, const int* __restrict__ rmap,
                             int* __restrict__ roots, int* __restrict__ counts) {
    int n = blockIdx.x * blockDim.x + threadIdx.x;
    int r = rmap[wi[n]];
    roots[n] = r;
    atomicAdd(&counts[r], 1);
}

// one wave per output row; 4 rows (4 waves) per block; 2048 roots * 128 rows / 4 = 65536 blocks
__global__ void k_matvec(const float* __restrict__ M, const float* __restrict__ e,
                         const float* __restrict__ b, float* __restrict__ g) {
    int r   = blockIdx.x >> 5;
    int row = ((blockIdx.x & 31) << 2) + (threadIdx.x >> 6);
    int lane = threadIdx.x & 63;
    const float2* mrow = (const float2*)(M + ((size_t)r * EMB + row) * EMB);
    const float2* ev   = (const float2*)(e + (size_t)r * EMB);
    float2 m  = mrow[lane];
    float2 ee = ev[lane];
    float acc = m.x * ee.x + m.y * ee.y;
#pragma unroll
    for (int off = 32; off; off >>= 1) acc += __shfl_xor(acc, off, 64);
    if (lane == 0) g[r * EMB + row] = acc + b[r * EMB + row];
}

__global__ void k_boost_sum(const float* __restrict__ w, const int* __restrict__ roots,
                            const int* __restrict__ counts, float* __restrict__ x,
                            float* __restrict__ denom) {
    __shared__ float sred[4];
    int n = blockIdx.x * blockDim.x + threadIdx.x;
    float c = (float)(counts[roots[n]] - 1);
    float v = w[n] * exp2f(c * LOG2_BOOST) + EPS;
    x[n] = v;
#pragma unroll
    for (int off = 32; off; off >>= 1) v += __shfl_xor(v, off, 64);
    int wave = threadIdx.x >> 6, lane = threadIdx.x & 63;
    if (lane == 0) sred[wave] = v;
    __syncthreads();
    if (threadIdx.x == 0) atomicAdd(denom, sred[0] + sred[1] + sred[2] + sred[3]);
}

// one float4 per thread: N*32 threads
__global__ void k_out(const float* __restrict__ g, const int* __restrict__ roots,
                      const float* __restrict__ x, const float* __restrict__ denom,
                      float4* __restrict__ out) {
    int idx = blockIdx.x * blockDim.x + threadIdx.x;
    int n = idx >> 5;
    float s = x[n] / *denom;
    const float4* gp = (const float4*)(g + ((size_t)roots[n] << 7));
    float4 v = gp[idx & 31];
    v.x *= s; v.y *= s; v.z *= s; v.w *= s;
    out[idx] = v;
}

extern "C" void kernel_launch(void* const* d_in, const int* in_sizes, int n_in,
                              void* d_out, int out_size, void* d_ws, size_t ws_size,
                              hipStream_t stream) {
    const float* emb  = (const float*)d_in[0];
    const float* M    = (const float*)d_in[1];
    const float* bias = (const float*)d_in[2];
    const float* attw = (const float*)d_in[3];
    const int*   wi   = (const int*)d_in[4];
    const int*   rmap = (const int*)d_in[5];
    float* out = (float*)d_out;

    char* ws = (char*)d_ws;
    int*   counts = (int*)(ws);
    float* denom  = (float*)(ws + 8192);
    int*   roots  = (int*)(ws + 16384);
    float* x      = (float*)(ws + 81920);
    float* g      = (float*)(ws + 147456);

    hipMemsetAsync(ws, 0, 8196, stream);                                   // counts + denom
    k_roots_hist<<<N_WORDS / 256, 256, 0, stream>>>(wi, rmap, roots, counts);
    k_matvec<<<NROOTS * 32, 256, 0, stream>>>(M, emb, bias, g);
    k_boost_sum<<<N_WORDS / 256, 256, 0, stream>>>(attw, roots, counts, x, denom);
    k_out<<<N_WORDS * 32 / 256, 256, 0, stream>>>(g, roots, x, denom, (float4*)out);
}

// Round 2
// 207.174 us; speedup vs baseline: 1.1231x; 1.1231x over previous
//
#include <hip/hip_runtime.h>

#define N_WORDS 16384
#define EMB 128
#define NROOTS 2048
#define EPS 1e-8f
#define LOG2_BOOST 0.5849625007211562f   // log2(1.5)

#define MV_BLOCKS 32768                  // 2048 roots * 16 blocks (8 rows/block)

// ws layout (bytes):
//   [0,     8192)   counts   int[2048]     (memset to 0)
//   [8192, 73728)   roots    int[16384]
//   [73728,73984)   partials float[64]
//   [73984, ...)    g        float[2048*128]

// Fused: blocks [0,32768) do per-root matvec rows; blocks [32768,32832) do hist.
__global__ void k_fused(const float* __restrict__ M, const float* __restrict__ e,
                        const float* __restrict__ bias, float* __restrict__ g,
                        const int* __restrict__ wi, const int* __restrict__ rmap,
                        int* __restrict__ roots, int* __restrict__ counts) {
    if (blockIdx.x >= MV_BLOCKS) {
        int n = (blockIdx.x - MV_BLOCKS) * 256 + threadIdx.x;
        int r = rmap[wi[n]];
        roots[n] = r;
        atomicAdd(&counts[r], 1);
        return;
    }
    int b = blockIdx.x;
    int r = b >> 4;                                  // 16 blocks per root
    int wave = threadIdx.x >> 6;
    int lane = threadIdx.x & 63;
    int row = ((b & 15) << 3) + (wave << 1) + (lane >> 5);   // 8 rows/block, 2 rows/wave
    int col = (lane & 31) << 2;                               // 32 lanes * float4 = 128 cols
    size_t rbase = (size_t)r << 7;
    const float4 m  = *(const float4*)(M + (rbase + row) * EMB + col);
    const float4 ee = *(const float4*)(e + rbase + col);
    float acc = fmaf(m.x, ee.x, fmaf(m.y, ee.y, fmaf(m.z, ee.z, m.w * ee.w)));
#pragma unroll
    for (int off = 16; off; off >>= 1) acc += __shfl_xor(acc, off, 64);  // within 32-lane group
    if ((lane & 31) == 0) g[rbase + row] = acc + bias[rbase + row];
}

__global__ void k_partial(const float* __restrict__ w, const int* __restrict__ roots,
                          const int* __restrict__ counts, float* __restrict__ partials) {
    __shared__ float sred[4];
    int n = blockIdx.x * 256 + threadIdx.x;
    float c = (float)(counts[roots[n]] - 1);
    float v = fmaf(w[n], exp2f(c * LOG2_BOOST), EPS);
#pragma unroll
    for (int off = 32; off; off >>= 1) v += __shfl_xor(v, off, 64);
    int wave = threadIdx.x >> 6, lane = threadIdx.x & 63;
    if (lane == 0) sred[wave] = v;
    __syncthreads();
    if (threadIdx.x == 0) partials[blockIdx.x] = sred[0] + sred[1] + sred[2] + sred[3];
}

// one float4 per thread; each wave re-reduces the 64 partials (L2-resident, 256 B)
__global__ void k_out(const float* __restrict__ g, const int* __restrict__ roots,
                      const int* __restrict__ counts, const float* __restrict__ w,
                      const float* __restrict__ partials, float4* __restrict__ out) {
    int lane = threadIdx.x & 63;
    float d = partials[lane];
#pragma unroll
    for (int off = 32; off; off >>= 1) d += __shfl_xor(d, off, 64);   // all lanes = total
    int idx = blockIdx.x * 256 + threadIdx.x;
    int n = idx >> 5;
    int r = roots[n];
    float c = (float)(counts[r] - 1);
    float v = fmaf(w[n], exp2f(c * LOG2_BOOST), EPS);
    float s = v / d;
    float4 gv = ((const float4*)(g + ((size_t)r << 7)))[idx & 31];
    gv.x *= s; gv.y *= s; gv.z *= s; gv.w *= s;
    out[idx] = gv;
}

extern "C" void kernel_launch(void* const* d_in, const int* in_sizes, int n_in,
                              void* d_out, int out_size, void* d_ws, size_t ws_size,
                              hipStream_t stream) {
    const float* emb  = (const float*)d_in[0];
    const float* M    = (const float*)d_in[1];
    const float* bias = (const float*)d_in[2];
    const float* attw = (const float*)d_in[3];
    const int*   wi   = (const int*)d_in[4];
    const int*   rmap = (const int*)d_in[5];
    float* out = (float*)d_out;

    char* ws = (char*)d_ws;
    int*   counts   = (int*)(ws);
    int*   roots    = (int*)(ws + 8192);
    float* partials = (float*)(ws + 73728);
    float* g        = (float*)(ws + 73984);

    hipMemsetAsync(counts, 0, NROOTS * sizeof(int), stream);
    k_fused<<<MV_BLOCKS + N_WORDS / 256, 256, 0, stream>>>(M, emb, bias, g, wi, rmap, roots, counts);
    k_partial<<<N_WORDS / 256, 256, 0, stream>>>(attw, roots, counts, partials);
    k_out<<<N_WORDS * (EMB / 4) / 256, 256, 0, stream>>>(g, roots, counts, attw, partials, (float4*)out);
}